// Round 5
// baseline (177.066 us; speedup 1.0000x reference)
//
#include <hip/hip_runtime.h>

#define NQ 4096
#define NS 8192
#define DD 256
#define NC 64
#define INFV 1000.0f

typedef __attribute__((ext_vector_type(8))) __bf16 bf16x8;
typedef __attribute__((ext_vector_type(4))) float floatx4;

__device__ inline unsigned short f2bf(float f) {
    unsigned int u = __builtin_bit_cast(unsigned int, f);
    unsigned int r = (u + 0x7FFFu + ((u >> 16) & 1u)) >> 16;
    return (unsigned short)r;
}

__device__ inline bf16x8 cvt8(const float* p) {
    unsigned short tmp[8];
#pragma unroll
    for (int i = 0; i < 8; ++i) tmp[i] = f2bf(p[i]);
    return *(bf16x8*)tmp;
}

// ---- K1: convert to bf16 + norms + diagonal dot + class counts (fused) ----
__global__ __launch_bounds__(256) void k_prep(const float* __restrict__ xq,
                                              const float* __restrict__ xs,
                                              const int* __restrict__ ys,
                                              unsigned short* __restrict__ xqh,
                                              unsigned short* __restrict__ xsh,
                                              float* __restrict__ nq2,
                                              float* __restrict__ ns2,
                                              float* __restrict__ ldot,
                                              int* __restrict__ counts,
                                              int* __restrict__ qcounts) {
    int row = blockIdx.x * 4 + (threadIdx.x >> 6);
    int lane = threadIdx.x & 63;
    if (row < NQ) {
        float4 a = ((const float4*)(xq + (size_t)row * DD))[lane];
        float4 b = ((const float4*)(xs + (size_t)row * DD))[lane];
        float s = a.x * a.x + a.y * a.y + a.z * a.z + a.w * a.w;
        float d = a.x * b.x + a.y * b.y + a.z * b.z + a.w * b.w;
        ((ushort4*)(xqh + (size_t)row * DD))[lane] =
            make_ushort4(f2bf(a.x), f2bf(a.y), f2bf(a.z), f2bf(a.w));
#pragma unroll
        for (int off = 32; off; off >>= 1) {
            s += __shfl_xor(s, off, 64);
            d += __shfl_xor(d, off, 64);
        }
        if (lane == 0) { nq2[row] = s; ldot[row] = d; }
    } else {
        int r = row - NQ;
        float4 v = ((const float4*)(xs + (size_t)r * DD))[lane];
        float s = v.x * v.x + v.y * v.y + v.z * v.z + v.w * v.w;
        ((ushort4*)(xsh + (size_t)r * DD))[lane] =
            make_ushort4(f2bf(v.x), f2bf(v.y), f2bf(v.z), f2bf(v.w));
#pragma unroll
        for (int off = 32; off; off >>= 1) s += __shfl_xor(s, off, 64);
        if (lane == 0) {
            ns2[r] = s;
            int c = ys[r];
            atomicAdd(&counts[c], 1);
            if (r < NQ) atomicAdd(&qcounts[c], 1);
        }
    }
}

// ---- K2: scatter into class buckets (each block redundantly scans counts) ----
__global__ __launch_bounds__(256) void k_scat(const int* __restrict__ ys,
                                              const int* __restrict__ counts,
                                              const int* __restrict__ qcounts,
                                              int* __restrict__ soff_g,
                                              int* __restrict__ qoff_g,
                                              int* __restrict__ scur,
                                              int* __restrict__ qcur,
                                              int* __restrict__ sperm,
                                              int* __restrict__ qperm) {
    __shared__ int soff_sh[NC], qoff_sh[NC];
    const int tid = threadIdx.x;
    if (tid < NC) {
        int cv = counts[tid], qv = qcounts[tid];
        int x = cv, xb = qv;
#pragma unroll
        for (int off = 1; off < 64; off <<= 1) {
            int y0 = __shfl_up(x, off, 64);
            int y1 = __shfl_up(xb, off, 64);
            if (tid >= off) { x += y0; xb += y1; }
        }
        soff_sh[tid] = x - cv;
        qoff_sh[tid] = xb - qv;
        if (blockIdx.x == 0) { soff_g[tid] = x - cv; qoff_g[tid] = xb - qv; }
    }
    __syncthreads();
    int j = blockIdx.x * 256 + tid;
    int c = ys[j];
    int p = atomicAdd(&scur[c], 1);
    sperm[soff_sh[c] + p] = j;
    if (j < NQ) {
        int q = atomicAdd(&qcur[c], 1);
        qperm[qoff_sh[c] + q] = j;
    }
}

// ---- K3: class centroids, one block per class, direct store (c-major) ----
__global__ __launch_bounds__(256) void k_cent(const float* __restrict__ xs,
                                              const float* __restrict__ ns2,
                                              const int* __restrict__ counts,
                                              const int* __restrict__ soff,
                                              const int* __restrict__ sperm,
                                              float* __restrict__ mcent,
                                              float* __restrict__ Sc) {
    __shared__ float red[4][256];
    __shared__ float sred[4];
    const int c = blockIdx.x;
    const int mc = counts[c];
    const int sbase = soff[c];
    const int tid = threadIdx.x;
    const int g = tid >> 6;
    const int lane = tid & 63;

    float4 acc = make_float4(0.f, 0.f, 0.f, 0.f);
    float sacc = 0.0f;
    for (int idx = g; idx < mc; idx += 4) {
        int row = sperm[sbase + idx];
        float4 v = ((const float4*)(xs + (size_t)row * DD))[lane];
        acc.x += v.x; acc.y += v.y; acc.z += v.z; acc.w += v.w;
        if (lane == 0) sacc += ns2[row];
    }
    ((float4*)red[g])[lane] = acc;
    if (lane == 0) sred[g] = sacc;
    __syncthreads();
    if (g == 0) {
        int k0 = lane * 4;
#pragma unroll
        for (int j = 0; j < 4; ++j)
            mcent[(size_t)c * DD + k0 + j] =
                red[0][k0 + j] + red[1][k0 + j] + red[2][k0 + j] + red[3][k0 + j];
        if (lane == 0) Sc[c] = sred[0] + sred[1] + sred[2] + sred[3];
    }
}

// ---- K4: positive logsumexp (class c, 16-query tile per block) ----
__global__ __launch_bounds__(256) void k_pos(const unsigned short* __restrict__ xqh,
                                             const unsigned short* __restrict__ xsh,
                                             const float* __restrict__ nq2,
                                             const float* __restrict__ ns2,
                                             const int* __restrict__ counts,
                                             const int* __restrict__ qcounts,
                                             const int* __restrict__ soff,
                                             const int* __restrict__ qoff,
                                             const int* __restrict__ sperm,
                                             const int* __restrict__ qperm,
                                             float* __restrict__ poslog) {
    __shared__ int qish[16];
    __shared__ float nqsh[16];
    __shared__ float msh[4][16], ssh[4][16];

    const int c = blockIdx.x;
    const int qc = qcounts[c];
    const int mc = counts[c];
    const int sbase = soff[c];
    const int qbase = qoff[c];
    const float ov = (mc > 1) ? -INFV : 0.0f;

    const int tid = threadIdx.x;
    const int lane = tid & 63;
    const int wave = tid >> 6;
    const int quad = lane >> 4;
    const int l15 = lane & 15;

    for (int q0 = blockIdx.y * 16; q0 < qc; q0 += 64) {
        __syncthreads();
        if (tid < 16) {
            int idx = q0 + tid;
            int qi = (idx < qc) ? qperm[qbase + idx] : -1;
            qish[tid] = qi;
            nqsh[tid] = (qi >= 0) ? nq2[qi] : 0.0f;
        }
        __syncthreads();

        int qrow = qish[l15];
        int qrowL = qrow < 0 ? 0 : qrow;
        const unsigned short* ap = xqh + (size_t)qrowL * DD + quad * 8;
        bf16x8 afr[8];
#pragma unroll
        for (int ks = 0; ks < 8; ++ks) afr[ks] = *(const bf16x8*)(ap + ks * 32);

        int qid[4];
        float nqr[4];
#pragma unroll
        for (int r = 0; r < 4; ++r) {
            qid[r] = qish[quad * 4 + r];
            nqr[r] = nqsh[quad * 4 + r];
        }

        float mrun[4], srun[4];
#pragma unroll
        for (int r = 0; r < 4; ++r) { mrun[r] = -1e30f; srun[r] = 0.0f; }

        for (int jt = wave * 16; jt < mc; jt += 64) {
            int jcol = jt + l15;
            bool valid = jcol < mc;
            int sj = valid ? sperm[sbase + jcol] : -1;
            int sjL = sj < 0 ? 0 : sj;
            float nsv = valid ? ns2[sjL] : 0.0f;
            const unsigned short* bp = xsh + (size_t)sjL * DD + quad * 8;
            floatx4 acc = (floatx4)0.0f;
#pragma unroll
            for (int ks = 0; ks < 8; ++ks) {
                bf16x8 bfr = *(const bf16x8*)(bp + ks * 32);
                acc = __builtin_amdgcn_mfma_f32_16x16x32_bf16(afr[ks], bfr, acc, 0, 0, 0);
            }
            if (valid) {
#pragma unroll
                for (int r = 0; r < 4; ++r) {
                    float v = fminf(acc[r] - 0.5f * (nqr[r] + nsv), 0.0f);
                    if (sj == qid[r]) v = ov;
                    float mn = fmaxf(mrun[r], v);
                    srun[r] = srun[r] * __expf(mrun[r] - mn) + __expf(v - mn);
                    mrun[r] = mn;
                }
            }
        }
#pragma unroll
        for (int r = 0; r < 4; ++r) {
#pragma unroll
            for (int off = 1; off < 16; off <<= 1) {
                float m2 = __shfl_xor(mrun[r], off, 64);
                float s2 = __shfl_xor(srun[r], off, 64);
                float mn = fmaxf(mrun[r], m2);
                srun[r] = srun[r] * __expf(mrun[r] - mn) + s2 * __expf(m2 - mn);
                mrun[r] = mn;
            }
            if (l15 == 0) {
                msh[wave][quad * 4 + r] = mrun[r];
                ssh[wave][quad * 4 + r] = srun[r];
            }
        }
        __syncthreads();
        if (tid < 16) {
            int qi = qish[tid];
            if (qi >= 0) {
                float m = -1e30f, s = 0.0f;
#pragma unroll
                for (int w = 0; w < 4; ++w) {
                    float mw = msh[w][tid], sw = ssh[w][tid];
                    float mn = fmaxf(m, mw);
                    s = s * __expf(m - mn) + sw * __expf(mw - mn);
                    m = mn;
                }
                poslog[qi] = m + __logf(s);
            }
        }
    }
}

// ---- K5: summed via centroid MFMA + per-row neg logsumexp -> block partials ----
__global__ __launch_bounds__(256) void k_final(const unsigned short* __restrict__ xqh,
                                               const float* __restrict__ mcent,
                                               const float* __restrict__ Sc,
                                               const int* __restrict__ counts,
                                               const int* __restrict__ yq,
                                               const float* __restrict__ nq2,
                                               const float* __restrict__ ns2,
                                               const float* __restrict__ ldot,
                                               const float* __restrict__ poslog,
                                               float* __restrict__ partial) {
    __shared__ float cntf[64], scs[64], nqs[64], ldts[64], ns2s[64], pls[64], red[64];
    __shared__ int ysh[64];

    const int b = blockIdx.x;
    const int tid = threadIdx.x;
    const int lane = tid & 63;
    const int wave = tid >> 6;
    const int quad = lane >> 4;
    const int l15 = lane & 15;

    if (tid < 64) {
        cntf[tid] = (float)counts[tid];
        scs[tid] = Sc[tid];
        int row = b * 64 + tid;
        nqs[tid] = nq2[row];
        ysh[tid] = yq[row];
        ldts[tid] = ldot[row];
        ns2s[tid] = ns2[row];
        pls[tid] = poslog[row];
    }
    __syncthreads();

    const unsigned short* ap = xqh + (size_t)(b * 64 + wave * 16 + l15) * DD + quad * 8;
    bf16x8 afr[8];
#pragma unroll
    for (int ks = 0; ks < 8; ++ks) afr[ks] = *(const bf16x8*)(ap + ks * 32);

    floatx4 acc[4];
#pragma unroll
    for (int n = 0; n < 4; ++n) acc[n] = (floatx4)0.0f;

#pragma unroll
    for (int n = 0; n < 4; ++n) {
        const float* bp = mcent + (size_t)(n * 16 + l15) * DD + quad * 8;
#pragma unroll
        for (int ks = 0; ks < 8; ++ks) {
            bf16x8 bfr = cvt8(bp + ks * 32);
            acc[n] = __builtin_amdgcn_mfma_f32_16x16x32_bf16(afr[ks], bfr, acc[n], 0, 0, 0);
        }
    }

#pragma unroll
    for (int r = 0; r < 4; ++r) {
        int rl = wave * 16 + quad * 4 + r;
        float nqv = nqs[rl];
        int y = ysh[rl];
        float vv[4];
#pragma unroll
        for (int n = 0; n < 4; ++n) {
            int col = n * 16 + l15;
            float cnt = cntf[col];
            float val = acc[n][r] - 0.5f * cnt * nqv - 0.5f * scs[col];
            float sub = (col == y) ? 1.0f : 0.0f;
            if (col == y) {
                float lii = ldts[rl] - 0.5f * (nqv + ns2s[rl]);
                val += ((cnt > 1.5f) ? -INFV : 0.0f) - lii;
            }
            vv[n] = val / (cnt - sub);
        }
        float m = fmaxf(fmaxf(vv[0], vv[1]), fmaxf(vv[2], vv[3]));
#pragma unroll
        for (int off = 1; off < 16; off <<= 1) m = fmaxf(m, __shfl_xor(m, off, 64));
        float e = __expf(vv[0] - m) + __expf(vv[1] - m) + __expf(vv[2] - m) +
                  __expf(vv[3] - m);
#pragma unroll
        for (int off = 1; off < 16; off <<= 1) e += __shfl_xor(e, off, 64);
        if (l15 == 0) red[rl] = (m + __logf(e) - pls[rl]) * (1.0f / (float)NQ);
    }
    __syncthreads();
    if (tid < 64) {
        float s = red[tid];
#pragma unroll
        for (int off = 32; off; off >>= 1) s += __shfl_xor(s, off, 64);
        if (tid == 0) partial[b] = s;
    }
}

// ---- K6: final 64-way sum -> out[0] (direct store, no zeroing needed) ----
__global__ void k_red(const float* __restrict__ partial, float* __restrict__ out) {
    int lane = threadIdx.x;
    float s = partial[lane];
#pragma unroll
    for (int off = 32; off; off >>= 1) s += __shfl_xor(s, off, 64);
    if (lane == 0) out[0] = s;
}

extern "C" void kernel_launch(void* const* d_in, const int* in_sizes, int n_in,
                              void* d_out, int out_size, void* d_ws, size_t ws_size,
                              hipStream_t stream) {
    const float* xq = (const float*)d_in[0];
    const int* yq = (const int*)d_in[1];
    const float* xs = (const float*)d_in[2];
    const int* ys = (const int*)d_in[3];
    float* out = (float*)d_out;
    char* ws = (char*)d_ws;

    unsigned short* xqh = (unsigned short*)(ws + 0);        // 2 MB
    unsigned short* xsh = (unsigned short*)(ws + 2097152);  // 4 MB
    float* nq2 = (float*)(ws + 6291456);     // 16 KB
    float* ns2 = (float*)(ws + 6307840);     // 32 KB
    int* counts = (int*)(ws + 6340608);      // 256 B (zeroed)
    int* qcounts = (int*)(ws + 6340864);     // 256 B (zeroed)
    int* scur = (int*)(ws + 6341120);        // 256 B (zeroed)
    int* qcur = (int*)(ws + 6341376);        // 256 B (zeroed)
    int* soff = (int*)(ws + 6341632);
    int* qoff = (int*)(ws + 6341888);
    int* sperm = (int*)(ws + 6342144);       // 32 KB
    int* qperm = (int*)(ws + 6374912);       // 16 KB
    float* poslog = (float*)(ws + 6391296);  // 16 KB
    float* ldot = (float*)(ws + 6407680);    // 16 KB
    float* mcent = (float*)(ws + 6424064);   // 64 KB fp32 c-major [c*256+k]
    float* Sc = (float*)(ws + 6489600);      // 256 B
    float* partial = (float*)(ws + 6489856); // 256 B

    hipMemsetAsync(ws + 6340608, 0, 1024, stream);  // counts,qcounts,scur,qcur

    k_prep<<<dim3((NQ + NS) / 4), dim3(256), 0, stream>>>(xq, xs, ys, xqh, xsh, nq2,
                                                          ns2, ldot, counts, qcounts);
    k_scat<<<dim3(NS / 256), dim3(256), 0, stream>>>(ys, counts, qcounts, soff, qoff,
                                                     scur, qcur, sperm, qperm);
    k_cent<<<dim3(NC), dim3(256), 0, stream>>>(xs, ns2, counts, soff, sperm, mcent, Sc);
    k_pos<<<dim3(NC, 4), dim3(256), 0, stream>>>(xqh, xsh, nq2, ns2, counts, qcounts,
                                                 soff, qoff, sperm, qperm, poslog);
    k_final<<<dim3(64), dim3(256), 0, stream>>>(xqh, mcent, Sc, counts, yq, nq2, ns2,
                                                ldot, poslog, partial);
    k_red<<<dim3(1), dim3(64), 0, stream>>>(partial, out);
}

// Round 6
// 117.669 us; speedup vs baseline: 1.5048x; 1.5048x over previous
//
#include <hip/hip_runtime.h>

#define NQ 4096
#define NS 8192
#define DD 256
#define NC 64
#define INFV 1000.0f

typedef __attribute__((ext_vector_type(8))) __bf16 bf16x8;
typedef __attribute__((ext_vector_type(4))) float floatx4;

__device__ inline unsigned short f2bf(float f) {
    unsigned int u = __builtin_bit_cast(unsigned int, f);
    unsigned int r = (u + 0x7FFFu + ((u >> 16) & 1u)) >> 16;
    return (unsigned short)r;
}

__device__ inline bf16x8 cvt8(const float* p) {
    unsigned short tmp[8];
#pragma unroll
    for (int i = 0; i < 8; ++i) tmp[i] = f2bf(p[i]);
    return *(bf16x8*)tmp;
}

// ---- K1: convert to bf16 + norms + diagonal dot (NO atomics) ----
__global__ __launch_bounds__(256) void k_prep(const float* __restrict__ xq,
                                              const float* __restrict__ xs,
                                              unsigned short* __restrict__ xqh,
                                              unsigned short* __restrict__ xsh,
                                              float* __restrict__ nq2,
                                              float* __restrict__ ns2,
                                              float* __restrict__ ldot) {
    int row = blockIdx.x * 4 + (threadIdx.x >> 6);
    int lane = threadIdx.x & 63;
    if (row < NQ) {
        float4 a = ((const float4*)(xq + (size_t)row * DD))[lane];
        float4 b = ((const float4*)(xs + (size_t)row * DD))[lane];
        float s = a.x * a.x + a.y * a.y + a.z * a.z + a.w * a.w;
        float d = a.x * b.x + a.y * b.y + a.z * b.z + a.w * b.w;
        ((ushort4*)(xqh + (size_t)row * DD))[lane] =
            make_ushort4(f2bf(a.x), f2bf(a.y), f2bf(a.z), f2bf(a.w));
#pragma unroll
        for (int off = 32; off; off >>= 1) {
            s += __shfl_xor(s, off, 64);
            d += __shfl_xor(d, off, 64);
        }
        if (lane == 0) { nq2[row] = s; ldot[row] = d; }
    } else {
        int r = row - NQ;
        float4 v = ((const float4*)(xs + (size_t)r * DD))[lane];
        float s = v.x * v.x + v.y * v.y + v.z * v.z + v.w * v.w;
        ((ushort4*)(xsh + (size_t)r * DD))[lane] =
            make_ushort4(f2bf(v.x), f2bf(v.y), f2bf(v.z), f2bf(v.w));
#pragma unroll
        for (int off = 32; off; off >>= 1) s += __shfl_xor(s, off, 64);
        if (lane == 0) ns2[r] = s;
    }
}

// ---- K1b: class histogram, LDS-first (32 global atomics per class total) ----
__global__ __launch_bounds__(256) void k_hist(const int* __restrict__ ys,
                                              int* __restrict__ counts,
                                              int* __restrict__ qcounts) {
    __shared__ int h[NC], hq[NC];
    const int tid = threadIdx.x;
    if (tid < NC) { h[tid] = 0; hq[tid] = 0; }
    __syncthreads();
    int j = blockIdx.x * 256 + tid;
    int c = ys[j];
    atomicAdd(&h[c], 1);
    if (j < NQ) atomicAdd(&hq[c], 1);
    __syncthreads();
    if (tid < NC) {
        if (h[tid]) atomicAdd(&counts[tid], h[tid]);
        if (hq[tid]) atomicAdd(&qcounts[tid], hq[tid]);
    }
}

// ---- K2: two-level scatter: block LDS hist -> chunk reservation -> LDS rank ----
__global__ __launch_bounds__(256) void k_scat(const int* __restrict__ ys,
                                              const int* __restrict__ counts,
                                              const int* __restrict__ qcounts,
                                              int* __restrict__ soff_g,
                                              int* __restrict__ qoff_g,
                                              int* __restrict__ scur,
                                              int* __restrict__ qcur,
                                              int* __restrict__ sperm,
                                              int* __restrict__ qperm) {
    __shared__ int soff_sh[NC], qoff_sh[NC];
    __shared__ int h[NC], hq[NC], base[NC], baseq[NC], cur[NC], curq[NC];
    const int tid = threadIdx.x;
    if (tid < NC) { h[tid] = 0; hq[tid] = 0; cur[tid] = 0; curq[tid] = 0; }
    if (tid < NC) {
        int cv = counts[tid], qv = qcounts[tid];
        int x = cv, xb = qv;
#pragma unroll
        for (int off = 1; off < 64; off <<= 1) {
            int y0 = __shfl_up(x, off, 64);
            int y1 = __shfl_up(xb, off, 64);
            if (tid >= off) { x += y0; xb += y1; }
        }
        soff_sh[tid] = x - cv;
        qoff_sh[tid] = xb - qv;
        if (blockIdx.x == 0) { soff_g[tid] = x - cv; qoff_g[tid] = xb - qv; }
    }
    __syncthreads();
    const int j = blockIdx.x * 256 + tid;
    const int c = ys[j];
    const bool isq = j < NQ;
    atomicAdd(&h[c], 1);
    if (isq) atomicAdd(&hq[c], 1);
    __syncthreads();
    if (tid < NC) {
        base[tid] = h[tid] ? atomicAdd(&scur[tid], h[tid]) : 0;
        baseq[tid] = hq[tid] ? atomicAdd(&qcur[tid], hq[tid]) : 0;
    }
    __syncthreads();
    int rank = atomicAdd(&cur[c], 1);
    sperm[soff_sh[c] + base[c] + rank] = j;
    if (isq) {
        int rq = atomicAdd(&curq[c], 1);
        qperm[qoff_sh[c] + baseq[c] + rq] = j;
    }
}

// ---- K3: class centroids, (NC,4) grid, spread atomic flush (c-major) ----
__global__ __launch_bounds__(256) void k_cent(const float* __restrict__ xs,
                                              const float* __restrict__ ns2,
                                              const int* __restrict__ counts,
                                              const int* __restrict__ soff,
                                              const int* __restrict__ sperm,
                                              float* __restrict__ mcent,
                                              float* __restrict__ Sc) {
    __shared__ float red[4][256];
    __shared__ float sred[4];
    const int c = blockIdx.x;
    const int yb = blockIdx.y;
    const int mc = counts[c];
    const int sbase = soff[c];
    const int tid = threadIdx.x;
    const int g = tid >> 6;
    const int lane = tid & 63;

    float4 acc = make_float4(0.f, 0.f, 0.f, 0.f);
    float sacc = 0.0f;
    for (int idx = yb * 4 + g; idx < mc; idx += 16) {
        int row = sperm[sbase + idx];
        float4 v = ((const float4*)(xs + (size_t)row * DD))[lane];
        acc.x += v.x; acc.y += v.y; acc.z += v.z; acc.w += v.w;
        if (lane == 0) sacc += ns2[row];
    }
    ((float4*)red[g])[lane] = acc;
    if (lane == 0) sred[g] = sacc;
    __syncthreads();
    if (g == 0) {
        int k0 = lane * 4;
#pragma unroll
        for (int j = 0; j < 4; ++j) {
            float v = red[0][k0 + j] + red[1][k0 + j] + red[2][k0 + j] + red[3][k0 + j];
            atomicAdd(&mcent[(size_t)c * DD + k0 + j], v);
        }
        if (lane == 0) atomicAdd(&Sc[c], sred[0] + sred[1] + sred[2] + sred[3]);
    }
}

// ---- K4: positive logsumexp (class c, 16-query tile per block) ----
__global__ __launch_bounds__(256) void k_pos(const unsigned short* __restrict__ xqh,
                                             const unsigned short* __restrict__ xsh,
                                             const float* __restrict__ nq2,
                                             const float* __restrict__ ns2,
                                             const int* __restrict__ counts,
                                             const int* __restrict__ qcounts,
                                             const int* __restrict__ soff,
                                             const int* __restrict__ qoff,
                                             const int* __restrict__ sperm,
                                             const int* __restrict__ qperm,
                                             float* __restrict__ poslog) {
    __shared__ int qish[16];
    __shared__ float nqsh[16];
    __shared__ float msh[4][16], ssh[4][16];

    const int c = blockIdx.x;
    const int qc = qcounts[c];
    const int mc = counts[c];
    const int sbase = soff[c];
    const int qbase = qoff[c];
    const float ov = (mc > 1) ? -INFV : 0.0f;

    const int tid = threadIdx.x;
    const int lane = tid & 63;
    const int wave = tid >> 6;
    const int quad = lane >> 4;
    const int l15 = lane & 15;

    for (int q0 = blockIdx.y * 16; q0 < qc; q0 += 64) {
        __syncthreads();
        if (tid < 16) {
            int idx = q0 + tid;
            int qi = (idx < qc) ? qperm[qbase + idx] : -1;
            qish[tid] = qi;
            nqsh[tid] = (qi >= 0) ? nq2[qi] : 0.0f;
        }
        __syncthreads();

        int qrow = qish[l15];
        int qrowL = qrow < 0 ? 0 : qrow;
        const unsigned short* ap = xqh + (size_t)qrowL * DD + quad * 8;
        bf16x8 afr[8];
#pragma unroll
        for (int ks = 0; ks < 8; ++ks) afr[ks] = *(const bf16x8*)(ap + ks * 32);

        int qid[4];
        float nqr[4];
#pragma unroll
        for (int r = 0; r < 4; ++r) {
            qid[r] = qish[quad * 4 + r];
            nqr[r] = nqsh[quad * 4 + r];
        }

        float mrun[4], srun[4];
#pragma unroll
        for (int r = 0; r < 4; ++r) { mrun[r] = -1e30f; srun[r] = 0.0f; }

        for (int jt = wave * 16; jt < mc; jt += 64) {
            int jcol = jt + l15;
            bool valid = jcol < mc;
            int sj = valid ? sperm[sbase + jcol] : -1;
            int sjL = sj < 0 ? 0 : sj;
            float nsv = valid ? ns2[sjL] : 0.0f;
            const unsigned short* bp = xsh + (size_t)sjL * DD + quad * 8;
            floatx4 acc = (floatx4)0.0f;
#pragma unroll
            for (int ks = 0; ks < 8; ++ks) {
                bf16x8 bfr = *(const bf16x8*)(bp + ks * 32);
                acc = __builtin_amdgcn_mfma_f32_16x16x32_bf16(afr[ks], bfr, acc, 0, 0, 0);
            }
            if (valid) {
#pragma unroll
                for (int r = 0; r < 4; ++r) {
                    float v = fminf(acc[r] - 0.5f * (nqr[r] + nsv), 0.0f);
                    if (sj == qid[r]) v = ov;
                    float mn = fmaxf(mrun[r], v);
                    srun[r] = srun[r] * __expf(mrun[r] - mn) + __expf(v - mn);
                    mrun[r] = mn;
                }
            }
        }
#pragma unroll
        for (int r = 0; r < 4; ++r) {
#pragma unroll
            for (int off = 1; off < 16; off <<= 1) {
                float m2 = __shfl_xor(mrun[r], off, 64);
                float s2 = __shfl_xor(srun[r], off, 64);
                float mn = fmaxf(mrun[r], m2);
                srun[r] = srun[r] * __expf(mrun[r] - mn) + s2 * __expf(m2 - mn);
                mrun[r] = mn;
            }
            if (l15 == 0) {
                msh[wave][quad * 4 + r] = mrun[r];
                ssh[wave][quad * 4 + r] = srun[r];
            }
        }
        __syncthreads();
        if (tid < 16) {
            int qi = qish[tid];
            if (qi >= 0) {
                float m = -1e30f, s = 0.0f;
#pragma unroll
                for (int w = 0; w < 4; ++w) {
                    float mw = msh[w][tid], sw = ssh[w][tid];
                    float mn = fmaxf(m, mw);
                    s = s * __expf(m - mn) + sw * __expf(mw - mn);
                    m = mn;
                }
                poslog[qi] = m + __logf(s);
            }
        }
    }
}

// ---- K5: summed via centroid MFMA + per-row neg logsumexp -> block partials ----
__global__ __launch_bounds__(256) void k_final(const unsigned short* __restrict__ xqh,
                                               const float* __restrict__ mcent,
                                               const float* __restrict__ Sc,
                                               const int* __restrict__ counts,
                                               const int* __restrict__ yq,
                                               const float* __restrict__ nq2,
                                               const float* __restrict__ ns2,
                                               const float* __restrict__ ldot,
                                               const float* __restrict__ poslog,
                                               float* __restrict__ partial) {
    __shared__ float cntf[64], scs[64], nqs[64], ldts[64], ns2s[64], pls[64], red[64];
    __shared__ int ysh[64];

    const int b = blockIdx.x;
    const int tid = threadIdx.x;
    const int lane = tid & 63;
    const int wave = tid >> 6;
    const int quad = lane >> 4;
    const int l15 = lane & 15;

    if (tid < 64) {
        cntf[tid] = (float)counts[tid];
        scs[tid] = Sc[tid];
        int row = b * 64 + tid;
        nqs[tid] = nq2[row];
        ysh[tid] = yq[row];
        ldts[tid] = ldot[row];
        ns2s[tid] = ns2[row];
        pls[tid] = poslog[row];
    }
    __syncthreads();

    const unsigned short* ap = xqh + (size_t)(b * 64 + wave * 16 + l15) * DD + quad * 8;
    bf16x8 afr[8];
#pragma unroll
    for (int ks = 0; ks < 8; ++ks) afr[ks] = *(const bf16x8*)(ap + ks * 32);

    floatx4 acc[4];
#pragma unroll
    for (int n = 0; n < 4; ++n) acc[n] = (floatx4)0.0f;

#pragma unroll
    for (int n = 0; n < 4; ++n) {
        const float* bp = mcent + (size_t)(n * 16 + l15) * DD + quad * 8;
#pragma unroll
        for (int ks = 0; ks < 8; ++ks) {
            bf16x8 bfr = cvt8(bp + ks * 32);
            acc[n] = __builtin_amdgcn_mfma_f32_16x16x32_bf16(afr[ks], bfr, acc[n], 0, 0, 0);
        }
    }

#pragma unroll
    for (int r = 0; r < 4; ++r) {
        int rl = wave * 16 + quad * 4 + r;
        float nqv = nqs[rl];
        int y = ysh[rl];
        float vv[4];
#pragma unroll
        for (int n = 0; n < 4; ++n) {
            int col = n * 16 + l15;
            float cnt = cntf[col];
            float val = acc[n][r] - 0.5f * cnt * nqv - 0.5f * scs[col];
            float sub = (col == y) ? 1.0f : 0.0f;
            if (col == y) {
                float lii = ldts[rl] - 0.5f * (nqv + ns2s[rl]);
                val += ((cnt > 1.5f) ? -INFV : 0.0f) - lii;
            }
            vv[n] = val / (cnt - sub);
        }
        float m = fmaxf(fmaxf(vv[0], vv[1]), fmaxf(vv[2], vv[3]));
#pragma unroll
        for (int off = 1; off < 16; off <<= 1) m = fmaxf(m, __shfl_xor(m, off, 64));
        float e = __expf(vv[0] - m) + __expf(vv[1] - m) + __expf(vv[2] - m) +
                  __expf(vv[3] - m);
#pragma unroll
        for (int off = 1; off < 16; off <<= 1) e += __shfl_xor(e, off, 64);
        if (l15 == 0) red[rl] = (m + __logf(e) - pls[rl]) * (1.0f / (float)NQ);
    }
    __syncthreads();
    if (tid < 64) {
        float s = red[tid];
#pragma unroll
        for (int off = 32; off; off >>= 1) s += __shfl_xor(s, off, 64);
        if (tid == 0) partial[b] = s;
    }
}

// ---- K6: final 64-way sum -> out[0] ----
__global__ void k_red(const float* __restrict__ partial, float* __restrict__ out) {
    int lane = threadIdx.x;
    float s = partial[lane];
#pragma unroll
    for (int off = 32; off; off >>= 1) s += __shfl_xor(s, off, 64);
    if (lane == 0) out[0] = s;
}

extern "C" void kernel_launch(void* const* d_in, const int* in_sizes, int n_in,
                              void* d_out, int out_size, void* d_ws, size_t ws_size,
                              hipStream_t stream) {
    const float* xq = (const float*)d_in[0];
    const int* yq = (const int*)d_in[1];
    const float* xs = (const float*)d_in[2];
    const int* ys = (const int*)d_in[3];
    float* out = (float*)d_out;
    char* ws = (char*)d_ws;

    unsigned short* xqh = (unsigned short*)(ws + 0);        // 2 MB
    unsigned short* xsh = (unsigned short*)(ws + 2097152);  // 4 MB
    float* nq2 = (float*)(ws + 6291456);     // 16 KB
    float* ns2 = (float*)(ws + 6307840);     // 32 KB
    int* counts = (int*)(ws + 6340608);      // 256 B (zeroed)
    int* qcounts = (int*)(ws + 6340864);     // 256 B (zeroed)
    int* scur = (int*)(ws + 6341120);        // 256 B (zeroed)
    int* qcur = (int*)(ws + 6341376);        // 256 B (zeroed)
    int* soff = (int*)(ws + 6341632);
    int* qoff = (int*)(ws + 6341888);
    int* sperm = (int*)(ws + 6342144);       // 32 KB
    int* qperm = (int*)(ws + 6374912);       // 16 KB
    float* poslog = (float*)(ws + 6391296);  // 16 KB
    float* ldot = (float*)(ws + 6407680);    // 16 KB
    float* mcent = (float*)(ws + 6424064);   // 64 KB fp32 c-major (zeroed)
    float* Sc = (float*)(ws + 6489600);      // 256 B (zeroed, contiguous w/ mcent)
    float* partial = (float*)(ws + 6489856); // 256 B

    hipMemsetAsync(ws + 6340608, 0, 1024, stream);   // counts,qcounts,scur,qcur
    hipMemsetAsync(ws + 6424064, 0, 65792, stream);  // mcent + Sc

    k_prep<<<dim3((NQ + NS) / 4), dim3(256), 0, stream>>>(xq, xs, xqh, xsh, nq2, ns2,
                                                          ldot);
    k_hist<<<dim3(NS / 256), dim3(256), 0, stream>>>(ys, counts, qcounts);
    k_scat<<<dim3(NS / 256), dim3(256), 0, stream>>>(ys, counts, qcounts, soff, qoff,
                                                     scur, qcur, sperm, qperm);
    k_cent<<<dim3(NC, 4), dim3(256), 0, stream>>>(xs, ns2, counts, soff, sperm, mcent,
                                                  Sc);
    k_pos<<<dim3(NC, 4), dim3(256), 0, stream>>>(xqh, xsh, nq2, ns2, counts, qcounts,
                                                 soff, qoff, sperm, qperm, poslog);
    k_final<<<dim3(64), dim3(256), 0, stream>>>(xqh, mcent, Sc, counts, yq, nq2, ns2,
                                                ldot, poslog, partial);
    k_red<<<dim3(1), dim3(64), 0, stream>>>(partial, out);
}